// Round 9
// baseline (238.731 us; speedup 1.0000x reference)
//
#include <hip/hip_runtime.h>
#include <hip/hip_bf16.h>
#include <stdint.h>

#define B_DIM 8
#define C_DIM 128
#define N_SP 2304
#define NT 18                      // 2304 / 128
#define NTRI 171                   // NT*(NT+1)/2
#define NTILES (2 * B_DIM * NTRI)  // 2736 tiles
#define GRID_G (NTILES / 2)        // 1368 blocks, 2 tiles each; %8==0

typedef __attribute__((ext_vector_type(8))) short short8;
typedef __attribute__((ext_vector_type(4))) float f32x4;

__device__ __forceinline__ uint32_t f2bf(float f) {
    uint32_t u = __float_as_uint(f);
    return (u + 0x7fffu + ((u >> 16) & 1u)) >> 16;    // RNE
}

// ---- prep: fp32 [C][N] -> normalized bf16 rows xcat[pair][b][n][256]
//      half0 = x_out/(||.||+eps), half1 = x_tgt/(||.||+eps); 16B chunks swizzled by n&7
__global__ __launch_bounds__(256) void prep_kernel(
    const float* __restrict__ x0, const float* __restrict__ x1,
    const float* __restrict__ x2, const float* __restrict__ x3,
    ushort* __restrict__ xcat, float* __restrict__ accum, int* __restrict__ ticket)
{
    __shared__ ushort stage[64 * 128];    // 16 KB, swizzled half-rows

    int bid = blockIdx.x;                 // 4 * 8 * 36 = 1152
    int tid = threadIdx.x;
    if (bid == 0) {
        if (tid < 64) accum[tid] = 0.f;   // replaces memset (ws re-poisoned 0xAA)
        if (tid == 64) *ticket = 0;
    }
    int t  = bid / 288;                   // tensor 0..3
    int b  = (bid / 36) % 8;
    int nb = bid % 36;
    int q   = tid & 3;                    // c-quarter
    int nl  = tid >> 2;                   // local n 0..63
    int n   = nb * 64 + nl;
    const float* x  = t == 0 ? x0 : t == 1 ? x1 : t == 2 ? x2 : x3;
    const float* xb = x + (size_t)b * (C_DIM * N_SP) + n;
    int sw = nl & 7;

    float v[32];
    float s = 0.f;
#pragma unroll
    for (int m = 0; m < 32; ++m) {
        v[m] = xb[(size_t)(q * 32 + m) * N_SP];
        s = fmaf(v[m], v[m], s);
    }
    // lanes 4k..4k+3 share n (differ in q): reduce across bits 0-1
    s += __shfl_xor(s, 1, 64);
    s += __shfl_xor(s, 2, 64);
    float r = 1.f / (sqrtf(s) + 1e-8f);

#pragma unroll
    for (int jj = 0; jj < 4; ++jj) {
        uint32_t w[4];
#pragma unroll
        for (int m2 = 0; m2 < 4; ++m2) {
            float a0 = v[jj * 8 + 2 * m2]     * r;
            float a1 = v[jj * 8 + 2 * m2 + 1] * r;
            w[m2] = f2bf(a0) | (f2bf(a1) << 16);
        }
        int J = q * 4 + jj;
        uint4 u; u.x = w[0]; u.y = w[1]; u.z = w[2]; u.w = w[3];
        *(uint4*)&stage[nl * 128 + ((J ^ sw) * 8)] = u;
    }
    __syncthreads();

    int pair = t & 1, half = t >> 1;      // (o0,t0)->pair0, (o1,t1)->pair1
    ushort* dstbase = xcat + ((size_t)(pair * 8 + b) * N_SP + (size_t)nb * 64) * 256
                    + half * 128;
    // 64 rows x 16 chunks of 16B, coalesced 256B runs
#pragma unroll
    for (int it = 0; it < 4; ++it) {
        int idx = it * 256 + tid;
        int row = idx >> 4, c = idx & 15;
        *(uint4*)(dstbase + (size_t)row * 256 + c * 8) =
            *(const uint4*)(stage + row * 128 + c * 8);
    }
}

// ---- gram: D = o-hat Gram minus t-hat Gram via K=256 concat (B t-half negated)
struct TileInfo { size_t base; int tn, tm; float w2; int pair; };

__device__ __forceinline__ TileInfo decode_tile(int g) {
    int pair = g / (B_DIM * NTRI);
    int rem  = g - pair * (B_DIM * NTRI);
    int b    = rem / NTRI;
    int t    = rem - b * NTRI;
    int tn = 0, cnt = NT;
    while (t >= cnt) { t -= cnt; --cnt; ++tn; }
    TileInfo ti;
    ti.tn = tn; ti.tm = tn + t;
    ti.base = (size_t)(pair * 8 + b) * N_SP * 256;
    ti.w2 = (tn == ti.tm) ? 1.f : 2.f;
    ti.pair = pair;
    return ti;
}

// one K=64 stage: waves 0,1 fill pA (rows of tile-row tn), waves 2,3 fill pB (tm)
#define STAGE(BASE, TN, TM, HH, HL)                                                 \
    {                                                                               \
        const ushort* sb = xcat + (BASE) +                                          \
            (size_t)(((wid & 2) ? (TM) : (TN)) * 128) * 256;                        \
        ushort* pp = (wid & 2) ? pB : pA;                                           \
        int i0 = (wid & 1) * 8;                                                     \
        _Pragma("unroll")                                                           \
        for (int i = 0; i < 8; ++i) {                                               \
            int ii = i0 + i;                                                        \
            int col = ii * 8 + (lane >> 3);                                         \
            const ushort* src = sb + (size_t)col * 256 + (HH) * 128 + (HL) * 64     \
                              + (lane & 7) * 8;                                     \
            __builtin_amdgcn_global_load_lds(                                       \
                (const __attribute__((address_space(1))) uint32_t*)src,             \
                (__attribute__((address_space(3))) uint32_t*)(pp + ii * 512),       \
                16, 0, 0);                                                          \
        }                                                                           \
    }

// K=64 compute; NEG=1 flips sign of B fragments (t-hat half)
#define COMPUTE(NEG)                                                                \
    _Pragma("unroll")                                                               \
    for (int s = 0; s < 2; ++s) {                                                   \
        short8 av[4], bv[4];                                                        \
        int g = lane >> 4;                                                          \
        _Pragma("unroll")                                                           \
        for (int i = 0; i < 4; ++i) {                                               \
            int ca = wrow * 64 + i * 16 + (lane & 15);                              \
            av[i] = *(const short8*)&pA[ca * 64 + ((s * 4 + g) ^ (ca & 7)) * 8];    \
            int cb = wcol * 64 + i * 16 + (lane & 15);                              \
            bv[i] = *(const short8*)&pB[cb * 64 + ((s * 4 + g) ^ (cb & 7)) * 8];    \
            if (NEG) {                                                              \
                _Pragma("unroll")                                                   \
                for (int d = 0; d < 4; ++d)                                         \
                    ((uint32_t*)&bv[i])[d] ^= 0x80008000u;                          \
            }                                                                       \
        }                                                                           \
        _Pragma("unroll")                                                           \
        for (int i = 0; i < 4; ++i)                                                 \
            _Pragma("unroll")                                                       \
            for (int j = 0; j < 4; ++j)                                             \
                acc[i][j] = __builtin_amdgcn_mfma_f32_16x16x32_bf16(                \
                    av[i], bv[j], acc[i][j], 0, 0, 0);                              \
    }

#define ZERO_ACC()                                                                  \
    _Pragma("unroll")                                                               \
    for (int i = 0; i < 4; ++i)                                                     \
        _Pragma("unroll")                                                           \
        for (int j = 0; j < 4; ++j)                                                 \
            acc[i][j] = (f32x4){0.f, 0.f, 0.f, 0.f};

#define EPILOGUE_ABS(W2, OUT)                                                       \
    {                                                                               \
        float lsum = 0.f;                                                           \
        _Pragma("unroll")                                                           \
        for (int i = 0; i < 4; ++i)                                                 \
            _Pragma("unroll")                                                       \
            for (int j = 0; j < 4; ++j)                                             \
                _Pragma("unroll")                                                   \
                for (int rr = 0; rr < 4; ++rr)                                      \
                    lsum += fabsf(acc[i][j][rr]);                                   \
        lsum *= (W2);                                                               \
        _Pragma("unroll")                                                           \
        for (int off = 32; off > 0; off >>= 1)                                      \
            lsum += __shfl_down(lsum, off, 64);                                     \
        OUT = lsum;                                                                 \
    }

__global__ __launch_bounds__(256, 4) void gram_kernel(
    const ushort* __restrict__ xcat, float* __restrict__ accum,
    int* __restrict__ ticket, float* __restrict__ out)
{
    __shared__ ushort pA[128 * 64];   // 16 KB: [128 cols][64 k], swizzled chunks
    __shared__ ushort pB[128 * 64];   // 16 KB
    __shared__ int lastflag;

    int bid0 = blockIdx.x;
    int bid  = (bid0 & 7) * (GRID_G / 8) + (bid0 >> 3);   // XCD chunking (bijective)

    TileInfo t0 = decode_tile(2 * bid);
    TileInfo t1 = decode_tile(2 * bid + 1);

    int tid  = threadIdx.x;
    int wid  = tid >> 6;
    int lane = tid & 63;
    int wrow = wid >> 1, wcol = wid & 1;

    f32x4 acc[4][4];
    ZERO_ACC();
    float sum0, sum1;

    // ---- tile 0: 4 serial rounds (single buffer; syncthreads drains gload_lds)
    STAGE(t0.base, t0.tn, t0.tm, 0, 0); __syncthreads();
    COMPUTE(0);                         __syncthreads();
    STAGE(t0.base, t0.tn, t0.tm, 0, 1); __syncthreads();
    COMPUTE(0);                         __syncthreads();
    STAGE(t0.base, t0.tn, t0.tm, 1, 0); __syncthreads();
    COMPUTE(1);                         __syncthreads();
    STAGE(t0.base, t0.tn, t0.tm, 1, 1); __syncthreads();
    COMPUTE(1);                         __syncthreads();

    // ---- tile 1 (tile0 epilogue overlaps first stage)
    STAGE(t1.base, t1.tn, t1.tm, 0, 0);
    EPILOGUE_ABS(t0.w2, sum0);
    ZERO_ACC();
    __syncthreads();
    COMPUTE(0);                         __syncthreads();
    STAGE(t1.base, t1.tn, t1.tm, 0, 1); __syncthreads();
    COMPUTE(0);                         __syncthreads();
    STAGE(t1.base, t1.tn, t1.tm, 1, 0); __syncthreads();
    COMPUTE(1);                         __syncthreads();
    STAGE(t1.base, t1.tn, t1.tm, 1, 1); __syncthreads();
    COMPUTE(1);
    EPILOGUE_ABS(t1.w2, sum1);

    if (lane == 0) {
        atomicAdd(&accum[t0.pair * 32 + (bid0 & 31)], sum0);
        atomicAdd(&accum[t1.pair * 32 + (bid0 & 31)], sum1);
    }

    // ---- last-block finalize (ticket): syncthreads drains vmcnt -> atomics retired
    __syncthreads();
    if (tid == 0) {
        __threadfence();
        int old = __hip_atomic_fetch_add(ticket, 1, __ATOMIC_ACQ_REL,
                                         __HIP_MEMORY_SCOPE_AGENT);
        lastflag = (old == GRID_G - 1);
    }
    __syncthreads();
    if (lastflag && tid < 64) {
        float s2 = __hip_atomic_load(&accum[tid], __ATOMIC_RELAXED,
                                     __HIP_MEMORY_SCOPE_AGENT);
#pragma unroll
        for (int off = 32; off > 0; off >>= 1) s2 += __shfl_down(s2, off, 64);
        if (tid == 0) out[0] = s2 * (1.0f / 42467328.0f);  // mean over 8*2304^2, x2
    }
}

extern "C" void kernel_launch(void* const* d_in, const int* in_sizes, int n_in,
                              void* d_out, int out_size, void* d_ws, size_t ws_size,
                              hipStream_t stream) {
    const float* o0 = (const float*)d_in[0];
    const float* o1 = (const float*)d_in[1];
    const float* t0 = (const float*)d_in[2];
    const float* t1 = (const float*)d_in[3];

    ushort* xcat  = (ushort*)d_ws;                                  // 18,874,368 B
    float*  accum = (float*)((char*)d_ws + (size_t)2 * 8 * N_SP * 512);
    int*    ticket = (int*)(accum + 128);

    prep_kernel<<<1152, 256, 0, stream>>>(o0, o1, t0, t1, xcat, accum, ticket);
    gram_kernel<<<GRID_G, 256, 0, stream>>>(xcat, accum, ticket, (float*)d_out);
}

// Round 10
// 187.542 us; speedup vs baseline: 1.2729x; 1.2729x over previous
//
#include <hip/hip_runtime.h>
#include <hip/hip_bf16.h>
#include <stdint.h>

#define B_DIM 8
#define C_DIM 128
#define N_SP 2304
#define NT 18                      // 2304 / 128
#define NTRI 171                   // NT*(NT+1)/2
#define NTILES (2 * B_DIM * NTRI)  // 2736 tiles
#define GRID_G (NTILES / 2)        // 1368 blocks, 2 tiles each; %8==0

typedef __attribute__((ext_vector_type(8))) short short8;
typedef __attribute__((ext_vector_type(4))) float f32x4;
typedef __attribute__((ext_vector_type(4))) uint32_t u32x4;

__device__ __forceinline__ uint32_t f2bf(float f) {
    uint32_t u = __float_as_uint(f);
    return (u + 0x7fffu + ((u >> 16) & 1u)) >> 16;    // RNE
}

// ---- prep: fp32 [C][N] -> normalized bf16 rows xcat[pair][b][n][256]
//      half0 = x_out/(||.||+eps), half1 = x_tgt/(||.||+eps); 16B chunks swizzled by n&7
__global__ __launch_bounds__(256) void prep_kernel(
    const float* __restrict__ x0, const float* __restrict__ x1,
    const float* __restrict__ x2, const float* __restrict__ x3,
    ushort* __restrict__ xcat, float* __restrict__ accum, int* __restrict__ ticket)
{
    __shared__ ushort stage[64 * 128];    // 16 KB, swizzled half-rows

    int bid = blockIdx.x;                 // 4 * 8 * 36 = 1152
    int tid = threadIdx.x;
    if (bid == 0) {
        if (tid < 64) accum[tid] = 0.f;   // replaces memset (ws re-poisoned 0xAA)
        if (tid == 64) *ticket = 0;
    }
    int t  = bid / 288;                   // tensor 0..3
    int b  = (bid / 36) % 8;
    int nb = bid % 36;
    int q   = tid & 3;                    // c-quarter
    int nl  = tid >> 2;                   // local n 0..63
    int n   = nb * 64 + nl;
    const float* x  = t == 0 ? x0 : t == 1 ? x1 : t == 2 ? x2 : x3;
    const float* xb = x + (size_t)b * (C_DIM * N_SP) + n;
    int sw = nl & 7;

    float v[32];
    float s = 0.f;
#pragma unroll
    for (int m = 0; m < 32; ++m) {
        v[m] = xb[(size_t)(q * 32 + m) * N_SP];
        s = fmaf(v[m], v[m], s);
    }
    // lanes 4k..4k+3 share n (differ in q): reduce across bits 0-1
    s += __shfl_xor(s, 1, 64);
    s += __shfl_xor(s, 2, 64);
    float r = 1.f / (sqrtf(s) + 1e-8f);

#pragma unroll
    for (int jj = 0; jj < 4; ++jj) {
        uint32_t w[4];
#pragma unroll
        for (int m2 = 0; m2 < 4; ++m2) {
            float a0 = v[jj * 8 + 2 * m2]     * r;
            float a1 = v[jj * 8 + 2 * m2 + 1] * r;
            w[m2] = f2bf(a0) | (f2bf(a1) << 16);
        }
        int J = q * 4 + jj;
        uint4 u; u.x = w[0]; u.y = w[1]; u.z = w[2]; u.w = w[3];
        *(uint4*)&stage[nl * 128 + ((J ^ sw) * 8)] = u;
    }
    __syncthreads();

    int pair = t & 1, half = t >> 1;      // (o0,t0)->pair0, (o1,t1)->pair1
    ushort* dstbase = xcat + ((size_t)(pair * 8 + b) * N_SP + (size_t)nb * 64) * 256
                    + half * 128;
    // 64 rows x 16 chunks of 16B, coalesced 256B runs
#pragma unroll
    for (int it = 0; it < 4; ++it) {
        int idx = it * 256 + tid;
        int row = idx >> 4, c = idx & 15;
        *(uint4*)(dstbase + (size_t)row * 256 + c * 8) =
            *(const uint4*)(stage + row * 128 + c * 8);
    }
}

// ---- gram: D = o-hat Gram minus t-hat Gram via K=256 concat (B t-half negated)
struct TileInfo { size_t base; int tn, tm; float w2; int pair; };

__device__ __forceinline__ TileInfo decode_tile(int g) {
    int pair = g / (B_DIM * NTRI);
    int rem  = g - pair * (B_DIM * NTRI);
    int b    = rem / NTRI;
    int t    = rem - b * NTRI;
    int tn = 0, cnt = NT;
    while (t >= cnt) { t -= cnt; --cnt; ++tn; }
    TileInfo ti;
    ti.tn = tn; ti.tm = tn + t;
    ti.base = (size_t)(pair * 8 + b) * N_SP * 256;
    ti.w2 = (tn == ti.tm) ? 1.f : 2.f;
    ti.pair = pair;
    return ti;
}

// one K=64 stage: waves 0,1 fill pA (rows of tile-row tn), waves 2,3 fill pB (tm)
#define STAGE(BASE, TN, TM, HH, HL)                                                 \
    {                                                                               \
        const ushort* sb = xcat + (BASE) +                                          \
            (size_t)(((wid & 2) ? (TM) : (TN)) * 128) * 256;                        \
        ushort* pp = (wid & 2) ? pB : pA;                                           \
        int i0 = (wid & 1) * 8;                                                     \
        _Pragma("unroll")                                                           \
        for (int i = 0; i < 8; ++i) {                                               \
            int ii = i0 + i;                                                        \
            int col = ii * 8 + (lane >> 3);                                         \
            const ushort* src = sb + (size_t)col * 256 + (HH) * 128 + (HL) * 64     \
                              + (lane & 7) * 8;                                     \
            __builtin_amdgcn_global_load_lds(                                       \
                (const __attribute__((address_space(1))) uint32_t*)src,             \
                (__attribute__((address_space(3))) uint32_t*)(pp + ii * 512),       \
                16, 0, 0);                                                          \
        }                                                                           \
    }

// K=64 compute; NEG=1 flips sign of B fragments (t-hat half) via value-level XOR
// (NO address-of on vector regs — R9's &bv[i] cast forced scratch allocation)
#define COMPUTE(NEG)                                                                \
    _Pragma("unroll")                                                               \
    for (int s = 0; s < 2; ++s) {                                                   \
        short8 av[4], bv[4];                                                        \
        int g = lane >> 4;                                                          \
        _Pragma("unroll")                                                           \
        for (int i = 0; i < 4; ++i) {                                               \
            int ca = wrow * 64 + i * 16 + (lane & 15);                              \
            av[i] = *(const short8*)&pA[ca * 64 + ((s * 4 + g) ^ (ca & 7)) * 8];    \
            int cb = wcol * 64 + i * 16 + (lane & 15);                              \
            short8 braw = *(const short8*)&pB[cb * 64 + ((s * 4 + g) ^ (cb & 7)) * 8]; \
            if (NEG) {                                                              \
                u32x4 ub = __builtin_bit_cast(u32x4, braw);                         \
                ub ^= 0x80008000u;                                                  \
                braw = __builtin_bit_cast(short8, ub);                              \
            }                                                                       \
            bv[i] = braw;                                                           \
        }                                                                           \
        _Pragma("unroll")                                                           \
        for (int i = 0; i < 4; ++i)                                                 \
            _Pragma("unroll")                                                       \
            for (int j = 0; j < 4; ++j)                                             \
                acc[i][j] = __builtin_amdgcn_mfma_f32_16x16x32_bf16(                \
                    av[i], bv[j], acc[i][j], 0, 0, 0);                              \
    }

#define ZERO_ACC()                                                                  \
    _Pragma("unroll")                                                               \
    for (int i = 0; i < 4; ++i)                                                     \
        _Pragma("unroll")                                                           \
        for (int j = 0; j < 4; ++j)                                                 \
            acc[i][j] = (f32x4){0.f, 0.f, 0.f, 0.f};

#define EPILOGUE_ABS(W2, OUT)                                                       \
    {                                                                               \
        float lsum = 0.f;                                                           \
        _Pragma("unroll")                                                           \
        for (int i = 0; i < 4; ++i)                                                 \
            _Pragma("unroll")                                                       \
            for (int j = 0; j < 4; ++j)                                             \
                _Pragma("unroll")                                                   \
                for (int rr = 0; rr < 4; ++rr)                                      \
                    lsum += fabsf(acc[i][j][rr]);                                   \
        lsum *= (W2);                                                               \
        _Pragma("unroll")                                                           \
        for (int off = 32; off > 0; off >>= 1)                                      \
            lsum += __shfl_down(lsum, off, 64);                                     \
        OUT = lsum;                                                                 \
    }

__global__ __launch_bounds__(256, 3) void gram_kernel(
    const ushort* __restrict__ xcat, float* __restrict__ accum,
    int* __restrict__ ticket, float* __restrict__ out)
{
    __shared__ ushort pA[128 * 64];   // 16 KB: [128 cols][64 k], swizzled chunks
    __shared__ ushort pB[128 * 64];   // 16 KB
    __shared__ int lastflag;

    int bid0 = blockIdx.x;
    int bid  = (bid0 & 7) * (GRID_G / 8) + (bid0 >> 3);   // XCD chunking (bijective)

    TileInfo t0 = decode_tile(2 * bid);
    TileInfo t1 = decode_tile(2 * bid + 1);

    int tid  = threadIdx.x;
    int wid  = tid >> 6;
    int lane = tid & 63;
    int wrow = wid >> 1, wcol = wid & 1;

    f32x4 acc[4][4];
    ZERO_ACC();
    float sum0, sum1;

    // ---- tile 0: 4 serial rounds (single buffer; syncthreads drains gload_lds)
    STAGE(t0.base, t0.tn, t0.tm, 0, 0); __syncthreads();
    COMPUTE(0);                         __syncthreads();
    STAGE(t0.base, t0.tn, t0.tm, 0, 1); __syncthreads();
    COMPUTE(0);                         __syncthreads();
    STAGE(t0.base, t0.tn, t0.tm, 1, 0); __syncthreads();
    COMPUTE(1);                         __syncthreads();
    STAGE(t0.base, t0.tn, t0.tm, 1, 1); __syncthreads();
    COMPUTE(1);                         __syncthreads();

    // ---- tile 1 (tile0 epilogue overlaps first stage)
    STAGE(t1.base, t1.tn, t1.tm, 0, 0);
    EPILOGUE_ABS(t0.w2, sum0);
    ZERO_ACC();
    __syncthreads();
    COMPUTE(0);                         __syncthreads();
    STAGE(t1.base, t1.tn, t1.tm, 0, 1); __syncthreads();
    COMPUTE(0);                         __syncthreads();
    STAGE(t1.base, t1.tn, t1.tm, 1, 0); __syncthreads();
    COMPUTE(1);                         __syncthreads();
    STAGE(t1.base, t1.tn, t1.tm, 1, 1); __syncthreads();
    COMPUTE(1);
    EPILOGUE_ABS(t1.w2, sum1);

    if (lane == 0) {
        atomicAdd(&accum[t0.pair * 32 + (bid0 & 31)], sum0);
        atomicAdd(&accum[t1.pair * 32 + (bid0 & 31)], sum1);
    }

    // ---- last-block finalize (ticket): syncthreads drains vmcnt -> atomics retired
    __syncthreads();
    if (tid == 0) {
        __threadfence();
        int old = __hip_atomic_fetch_add(ticket, 1, __ATOMIC_ACQ_REL,
                                         __HIP_MEMORY_SCOPE_AGENT);
        lastflag = (old == GRID_G - 1);
    }
    __syncthreads();
    if (lastflag && tid < 64) {
        float s2 = __hip_atomic_load(&accum[tid], __ATOMIC_RELAXED,
                                     __HIP_MEMORY_SCOPE_AGENT);
#pragma unroll
        for (int off = 32; off > 0; off >>= 1) s2 += __shfl_down(s2, off, 64);
        if (tid == 0) out[0] = s2 * (1.0f / 42467328.0f);  // mean over 8*2304^2, x2
    }
}

extern "C" void kernel_launch(void* const* d_in, const int* in_sizes, int n_in,
                              void* d_out, int out_size, void* d_ws, size_t ws_size,
                              hipStream_t stream) {
    const float* o0 = (const float*)d_in[0];
    const float* o1 = (const float*)d_in[1];
    const float* t0 = (const float*)d_in[2];
    const float* t1 = (const float*)d_in[3];

    ushort* xcat  = (ushort*)d_ws;                                  // 18,874,368 B
    float*  accum = (float*)((char*)d_ws + (size_t)2 * 8 * N_SP * 512);
    int*    ticket = (int*)(accum + 128);

    prep_kernel<<<1152, 256, 0, stream>>>(o0, o1, t0, t1, xcat, accum, ticket);
    gram_kernel<<<GRID_G, 256, 0, stream>>>(xcat, accum, ticket, (float*)d_out);
}

// Round 11
// 165.999 us; speedup vs baseline: 1.4381x; 1.1298x over previous
//
#include <hip/hip_runtime.h>
#include <hip/hip_bf16.h>
#include <stdint.h>

#define B_DIM 8
#define C_DIM 128
#define N_SP 2304
#define NT 18                      // 2304 / 128
#define NTRI 171                   // NT*(NT+1)/2
#define NTILES (2 * B_DIM * NTRI)  // 2736 tiles
#define GRID_G (NTILES / 2)        // 1368 blocks, 2 tiles each; %8==0

typedef __attribute__((ext_vector_type(8))) short short8;
typedef __attribute__((ext_vector_type(4))) float f32x4;
typedef __attribute__((ext_vector_type(4))) uint32_t u32x4;

__device__ __forceinline__ uint32_t f2bf(float f) {
    uint32_t u = __float_as_uint(f);
    return (u + 0x7fffu + ((u >> 16) & 1u)) >> 16;    // RNE
}

// ---- prep: fp32 [C][N] -> normalized bf16 rows xcat[pair][b][n][256]
//      half0 = x_out/(||.||+eps), half1 = x_tgt/(||.||+eps); 16B chunks swizzled by n&7
__global__ __launch_bounds__(256) void prep_kernel(
    const float* __restrict__ x0, const float* __restrict__ x1,
    const float* __restrict__ x2, const float* __restrict__ x3,
    ushort* __restrict__ xcat, float* __restrict__ accum)
{
    __shared__ ushort stage[64 * 128];    // 16 KB, swizzled half-rows

    int bid = blockIdx.x;                 // 4 * 8 * 36 = 1152
    int tid = threadIdx.x;
    if (bid == 0 && tid < 64) accum[tid] = 0.f;   // replaces memset
    int t  = bid / 288;                   // tensor 0..3
    int b  = (bid / 36) % 8;
    int nb = bid % 36;
    int q   = tid & 3;                    // c-quarter
    int nl  = tid >> 2;                   // local n 0..63
    int n   = nb * 64 + nl;
    const float* x  = t == 0 ? x0 : t == 1 ? x1 : t == 2 ? x2 : x3;
    const float* xb = x + (size_t)b * (C_DIM * N_SP) + n;
    int sw = nl & 7;

    float v[32];
    float s = 0.f;
#pragma unroll
    for (int m = 0; m < 32; ++m) {
        v[m] = xb[(size_t)(q * 32 + m) * N_SP];
        s = fmaf(v[m], v[m], s);
    }
    // lanes 4k..4k+3 share n (differ in q): reduce across bits 0-1
    s += __shfl_xor(s, 1, 64);
    s += __shfl_xor(s, 2, 64);
    float r = 1.f / (sqrtf(s) + 1e-8f);

#pragma unroll
    for (int jj = 0; jj < 4; ++jj) {
        uint32_t w[4];
#pragma unroll
        for (int m2 = 0; m2 < 4; ++m2) {
            float a0 = v[jj * 8 + 2 * m2]     * r;
            float a1 = v[jj * 8 + 2 * m2 + 1] * r;
            w[m2] = f2bf(a0) | (f2bf(a1) << 16);
        }
        int J = q * 4 + jj;
        uint4 u; u.x = w[0]; u.y = w[1]; u.z = w[2]; u.w = w[3];
        *(uint4*)&stage[nl * 128 + ((J ^ sw) * 8)] = u;
    }
    __syncthreads();

    int pair = t & 1, half = t >> 1;      // (o0,t0)->pair0, (o1,t1)->pair1
    ushort* dstbase = xcat + ((size_t)(pair * 8 + b) * N_SP + (size_t)nb * 64) * 256
                    + half * 128;
    // 64 rows x 16 chunks of 16B, coalesced 256B runs
#pragma unroll
    for (int it = 0; it < 4; ++it) {
        int idx = it * 256 + tid;
        int row = idx >> 4, c = idx & 15;
        *(uint4*)(dstbase + (size_t)row * 256 + c * 8) =
            *(const uint4*)(stage + row * 128 + c * 8);
    }
}

// ---- gram: D = o-hat Gram minus t-hat Gram via K=256 concat (B t-half negated)
struct TileInfo { size_t base; int tn, tm; float w2; int pair; };

__device__ __forceinline__ TileInfo decode_tile(int g) {
    int pair = g / (B_DIM * NTRI);
    int rem  = g - pair * (B_DIM * NTRI);
    int b    = rem / NTRI;
    int t    = rem - b * NTRI;
    int tn = 0, cnt = NT;
    while (t >= cnt) { t -= cnt; --cnt; ++tn; }
    TileInfo ti;
    ti.tn = tn; ti.tm = tn + t;
    ti.base = (size_t)(pair * 8 + b) * N_SP * 256;
    ti.w2 = (tn == ti.tm) ? 1.f : 2.f;
    ti.pair = pair;
    return ti;
}

// one K=64 stage into buffer PA/PB: waves 0,1 fill PA (tile-row tn), waves 2,3 PB (tm)
#define STAGE(BASE, TN, TM, HH, HL, PA, PB)                                         \
    {                                                                               \
        const ushort* sb = xcat + (BASE) +                                          \
            (size_t)(((wid & 2) ? (TM) : (TN)) * 128) * 256;                        \
        ushort* pp = (wid & 2) ? (PB) : (PA);                                       \
        int i0 = (wid & 1) * 8;                                                     \
        _Pragma("unroll")                                                           \
        for (int i = 0; i < 8; ++i) {                                               \
            int ii = i0 + i;                                                        \
            int col = ii * 8 + (lane >> 3);                                         \
            const ushort* src = sb + (size_t)col * 256 + (HH) * 128 + (HL) * 64     \
                              + (lane & 7) * 8;                                     \
            __builtin_amdgcn_global_load_lds(                                       \
                (const __attribute__((address_space(1))) uint32_t*)src,             \
                (__attribute__((address_space(3))) uint32_t*)(pp + ii * 512),       \
                16, 0, 0);                                                          \
        }                                                                           \
    }

// K=64 compute; NEG=1 flips sign of B fragments (t-hat half) via value-level XOR
#define COMPUTE(NEG, PA, PB)                                                        \
    _Pragma("unroll")                                                               \
    for (int s = 0; s < 2; ++s) {                                                   \
        short8 av[4], bv[4];                                                        \
        int g = lane >> 4;                                                          \
        _Pragma("unroll")                                                           \
        for (int i = 0; i < 4; ++i) {                                               \
            int ca = wrow * 64 + i * 16 + (lane & 15);                              \
            av[i] = *(const short8*)&(PA)[ca * 64 + ((s * 4 + g) ^ (ca & 7)) * 8];  \
            int cb = wcol * 64 + i * 16 + (lane & 15);                              \
            short8 braw = *(const short8*)&(PB)[cb * 64 + ((s * 4 + g) ^ (cb & 7)) * 8]; \
            if (NEG) {                                                              \
                u32x4 ub = __builtin_bit_cast(u32x4, braw);                         \
                ub ^= 0x80008000u;                                                  \
                braw = __builtin_bit_cast(short8, ub);                              \
            }                                                                       \
            bv[i] = braw;                                                           \
        }                                                                           \
        _Pragma("unroll")                                                           \
        for (int i = 0; i < 4; ++i)                                                 \
            _Pragma("unroll")                                                       \
            for (int j = 0; j < 4; ++j)                                             \
                acc[i][j] = __builtin_amdgcn_mfma_f32_16x16x32_bf16(                \
                    av[i], bv[j], acc[i][j], 0, 0, 0);                              \
    }

#define ZERO_ACC()                                                                  \
    _Pragma("unroll")                                                               \
    for (int i = 0; i < 4; ++i)                                                     \
        _Pragma("unroll")                                                           \
        for (int j = 0; j < 4; ++j)                                                 \
            acc[i][j] = (f32x4){0.f, 0.f, 0.f, 0.f};

#define EPILOGUE_ABS(W2, OUT)                                                       \
    {                                                                               \
        float lsum = 0.f;                                                           \
        _Pragma("unroll")                                                           \
        for (int i = 0; i < 4; ++i)                                                 \
            _Pragma("unroll")                                                       \
            for (int j = 0; j < 4; ++j)                                             \
                _Pragma("unroll")                                                   \
                for (int rr = 0; rr < 4; ++rr)                                      \
                    lsum += fabsf(acc[i][j][rr]);                                   \
        lsum *= (W2);                                                               \
        _Pragma("unroll")                                                           \
        for (int off = 32; off > 0; off >>= 1)                                      \
            lsum += __shfl_down(lsum, off, 64);                                     \
        OUT = lsum;                                                                 \
    }

__global__ __launch_bounds__(256, 2) void gram_kernel(
    const ushort* __restrict__ xcat, float* __restrict__ accum)
{
    __shared__ ushort pA[2][128 * 64];   // dbuf, 32 KB
    __shared__ ushort pB[2][128 * 64];   // dbuf, 32 KB

    int bid0 = blockIdx.x;
    int bid  = (bid0 & 7) * (GRID_G / 8) + (bid0 >> 3);   // XCD chunking (bijective)

    TileInfo t0 = decode_tile(2 * bid);
    TileInfo t1 = decode_tile(2 * bid + 1);

    int tid  = threadIdx.x;
    int wid  = tid >> 6;
    int lane = tid & 63;
    int wrow = wid >> 1, wcol = wid & 1;

    f32x4 acc[4][4];
    ZERO_ACC();
    float sum0, sum1;

    // R5-validated schedule: issue STAGE(r+1) into the other buffer, then COMPUTE(r)
    STAGE(t0.base, t0.tn, t0.tm, 0, 0, pA[0], pB[0]);
    __syncthreads();
    STAGE(t0.base, t0.tn, t0.tm, 0, 1, pA[1], pB[1]);
    COMPUTE(0, pA[0], pB[0]);
    __syncthreads();
    STAGE(t0.base, t0.tn, t0.tm, 1, 0, pA[0], pB[0]);
    COMPUTE(0, pA[1], pB[1]);
    __syncthreads();
    STAGE(t0.base, t0.tn, t0.tm, 1, 1, pA[1], pB[1]);
    COMPUTE(1, pA[0], pB[0]);
    __syncthreads();
    STAGE(t1.base, t1.tn, t1.tm, 0, 0, pA[0], pB[0]);
    COMPUTE(1, pA[1], pB[1]);
    EPILOGUE_ABS(t0.w2, sum0);            // tile0 closes; overlaps t1's first stage
    ZERO_ACC();
    __syncthreads();
    STAGE(t1.base, t1.tn, t1.tm, 0, 1, pA[1], pB[1]);
    COMPUTE(0, pA[0], pB[0]);
    __syncthreads();
    STAGE(t1.base, t1.tn, t1.tm, 1, 0, pA[0], pB[0]);
    COMPUTE(0, pA[1], pB[1]);
    __syncthreads();
    STAGE(t1.base, t1.tn, t1.tm, 1, 1, pA[1], pB[1]);
    COMPUTE(1, pA[0], pB[0]);
    __syncthreads();
    COMPUTE(1, pA[1], pB[1]);
    EPILOGUE_ABS(t1.w2, sum1);

    if (lane == 0) {
        atomicAdd(&accum[t0.pair * 32 + (bid0 & 31)], sum0);
        atomicAdd(&accum[t1.pair * 32 + (bid0 & 31)], sum1);
    }
}

__global__ void finalize_kernel(const float* __restrict__ a, float* __restrict__ out) {
    float s = a[threadIdx.x];
#pragma unroll
    for (int off = 32; off > 0; off >>= 1) s += __shfl_down(s, off, 64);
    if (threadIdx.x == 0) out[0] = s * (1.0f / 42467328.0f);  // mean over 8*2304^2, x2
}

extern "C" void kernel_launch(void* const* d_in, const int* in_sizes, int n_in,
                              void* d_out, int out_size, void* d_ws, size_t ws_size,
                              hipStream_t stream) {
    const float* o0 = (const float*)d_in[0];
    const float* o1 = (const float*)d_in[1];
    const float* t0 = (const float*)d_in[2];
    const float* t1 = (const float*)d_in[3];

    ushort* xcat  = (ushort*)d_ws;                                  // 18,874,368 B
    float*  accum = (float*)((char*)d_ws + (size_t)2 * 8 * N_SP * 512);

    prep_kernel<<<1152, 256, 0, stream>>>(o0, o1, t0, t1, xcat, accum);
    gram_kernel<<<GRID_G, 256, 0, stream>>>(xcat, accum);
    finalize_kernel<<<1, 64, 0, stream>>>(accum, (float*)d_out);
}

// Round 12
// 149.334 us; speedup vs baseline: 1.5986x; 1.1116x over previous
//
#include <hip/hip_runtime.h>
#include <hip/hip_bf16.h>
#include <stdint.h>

#define B_DIM 8
#define C_DIM 128
#define N_SP 2304
#define NT 18                      // 2304 / 128
#define NTRI 171                   // NT*(NT+1)/2
#define NTILES (2 * B_DIM * NTRI)  // 2736 tiles, 1 per block; %8==0

typedef __attribute__((ext_vector_type(8))) short short8;
typedef __attribute__((ext_vector_type(4))) float f32x4;

__device__ __forceinline__ uint32_t f2bf(float f) {
    uint32_t u = __float_as_uint(f);
    return (u + 0x7fffu + ((u >> 16) & 1u)) >> 16;    // RNE
}

// ---- prep: fp32 [C][N] -> bf16 [N][C] rows (16B chunks swizzled by n&7) + fp32 rinv
//      (R5-validated; also zeroes accum)
__global__ __launch_bounds__(256) void prep_kernel(
    const float* __restrict__ x0, const float* __restrict__ x1,
    const float* __restrict__ x2, const float* __restrict__ x3,
    ushort* __restrict__ xt, float* __restrict__ rinv, float* __restrict__ accum)
{
    __shared__ ushort stage[64 * 128];    // 16 KB

    int bid = blockIdx.x;                 // 4 * 8 * 36
    if (bid == 0 && threadIdx.x < 64) accum[threadIdx.x] = 0.f;
    int t  = bid / 288;
    int b  = (bid / 36) % 8;
    int nb = bid % 36;
    int tid = threadIdx.x;
    int q   = tid & 3;                    // c-quarter
    int nl  = tid >> 2;                   // local n 0..63
    int n   = nb * 64 + nl;
    const float* x  = t == 0 ? x0 : t == 1 ? x1 : t == 2 ? x2 : x3;
    const float* xb = x + (size_t)b * (C_DIM * N_SP) + n;
    int sw = nl & 7;

    float s = 0.f;
#pragma unroll
    for (int jj = 0; jj < 4; ++jj) {
        uint32_t w[4];
#pragma unroll
        for (int m = 0; m < 4; ++m) {
            int c = q * 32 + jj * 8 + m * 2;
            float v0 = xb[(size_t)c * N_SP];
            float v1 = xb[(size_t)(c + 1) * N_SP];
            s = fmaf(v0, v0, s);
            s = fmaf(v1, v1, s);
            w[m] = f2bf(v0) | (f2bf(v1) << 16);
        }
        int J = q * 4 + jj;
        uint4 u; u.x = w[0]; u.y = w[1]; u.z = w[2]; u.w = w[3];
        *(uint4*)&stage[nl * 128 + ((J ^ sw) * 8)] = u;
    }
    s += __shfl_xor(s, 1, 64);
    s += __shfl_xor(s, 2, 64);
    if (q == 0) rinv[(size_t)(t * 8 + b) * N_SP + n] = 1.f / (sqrtf(s) + 1e-8f);

    __syncthreads();
    ushort* dst = xt + ((size_t)(t * 8 + b) * N_SP + (size_t)nb * 64) * 128;
#pragma unroll
    for (int it = 0; it < 4; ++it)
        *(uint4*)(dst + it * 2048 + tid * 8) = *(const uint4*)(stage + it * 2048 + tid * 8);
}

// ---- gram (R2-validated body + XCD swizzle + 4 blocks/CU):
//      1 tile/block, single-buffer serial rounds, two accumulators, rn epilogue
#define STAGE(xsrc, h)                                                              \
    {                                                                               \
        const ushort* sb = (wid & 2) ? (xsrc) + (size_t)tm * 16384                  \
                                     : (xsrc) + (size_t)tn * 16384;                 \
        ushort* pp = (wid & 2) ? pB : pA;                                           \
        int i0 = (wid & 1) * 8;                                                     \
        _Pragma("unroll")                                                           \
        for (int i = 0; i < 8; ++i) {                                               \
            int ii = i0 + i;                                                        \
            int col = ii * 8 + (lane >> 3);                                         \
            const ushort* src = sb + (size_t)col * 128 + (h) * 64 + (lane & 7) * 8; \
            __builtin_amdgcn_global_load_lds(                                       \
                (const __attribute__((address_space(1))) uint32_t*)src,             \
                (__attribute__((address_space(3))) uint32_t*)(pp + ii * 512),       \
                16, 0, 0);                                                          \
        }                                                                           \
    }

#define COMPUTE(ACC)                                                                \
    _Pragma("unroll")                                                               \
    for (int s = 0; s < 2; ++s) {                                                   \
        short8 av[4], bv[4];                                                        \
        int g = lane >> 4;                                                          \
        _Pragma("unroll")                                                           \
        for (int i = 0; i < 4; ++i) {                                               \
            int ca = wrow * 64 + i * 16 + (lane & 15);                              \
            av[i] = *(const short8*)&pA[ca * 64 + ((s * 4 + g) ^ (ca & 7)) * 8];    \
            int cb = wcol * 64 + i * 16 + (lane & 15);                              \
            bv[i] = *(const short8*)&pB[cb * 64 + ((s * 4 + g) ^ (cb & 7)) * 8];    \
        }                                                                           \
        _Pragma("unroll")                                                           \
        for (int i = 0; i < 4; ++i)                                                 \
            _Pragma("unroll")                                                       \
            for (int j = 0; j < 4; ++j)                                             \
                ACC[i][j] = __builtin_amdgcn_mfma_f32_16x16x32_bf16(                \
                    av[i], bv[j], ACC[i][j], 0, 0, 0);                              \
    }

__global__ __launch_bounds__(256, 4) void gram_kernel(
    const ushort* __restrict__ xt, const float* __restrict__ rinv,
    float* __restrict__ accum)
{
    __shared__ ushort pA[128 * 64];   // 16 KB
    __shared__ ushort pB[128 * 64];   // 16 KB
    __shared__ float rn[4][128];      // 2 KB
    __shared__ float wred[4];

    int bid0 = blockIdx.x;
    int bid  = (bid0 & 7) * (NTILES / 8) + (bid0 >> 3);   // XCD chunking (bijective)

    int pair = bid / (B_DIM * NTRI);
    int rem  = bid - pair * (B_DIM * NTRI);
    int b    = rem / NTRI;
    int t    = rem - b * NTRI;
    int tn = 0, cnt = NT;
    while (t >= cnt) { t -= cnt; --cnt; ++tn; }
    int tm = tn + t;

    const ushort* xo = xt + (size_t)(pair * 8 + b) * N_SP * 128;
    const ushort* xg = xt + (size_t)((pair + 2) * 8 + b) * N_SP * 128;
    const float*  ro = rinv + (size_t)(pair * 8 + b) * N_SP;
    const float*  rg = rinv + (size_t)((pair + 2) * 8 + b) * N_SP;

    int tid  = threadIdx.x;
    int wid  = tid >> 6;
    int lane = tid & 63;
    int wrow = wid >> 1, wcol = wid & 1;

    f32x4 acc_o[4][4], acc_t[4][4];
#pragma unroll
    for (int i = 0; i < 4; ++i)
#pragma unroll
        for (int j = 0; j < 4; ++j) {
            acc_o[i][j] = (f32x4){0.f, 0.f, 0.f, 0.f};
            acc_t[i][j] = (f32x4){0.f, 0.f, 0.f, 0.f};
        }

    STAGE(xo, 0);
    if (tid < 128) {
        rn[0][tid] = ro[tn * 128 + tid];
        rn[1][tid] = ro[tm * 128 + tid];
    } else {
        int q = tid - 128;
        rn[2][q] = rg[tn * 128 + q];
        rn[3][q] = rg[tm * 128 + q];
    }
    __syncthreads();
    COMPUTE(acc_o);
    __syncthreads();
    STAGE(xo, 1);
    __syncthreads();
    COMPUTE(acc_o);
    __syncthreads();
    STAGE(xg, 0);
    __syncthreads();
    COMPUTE(acc_t);
    __syncthreads();
    STAGE(xg, 1);
    __syncthreads();
    COMPUTE(acc_t);

    // epilogue: scale by inverse norms, abs-diff, reduce
    int fr = lane & 15, fq = lane >> 4;
    float co[4], cg[4];
#pragma unroll
    for (int j = 0; j < 4; ++j) {
        co[j] = rn[1][wcol * 64 + j * 16 + fr];
        cg[j] = rn[3][wcol * 64 + j * 16 + fr];
    }
    float w2 = (tn == tm) ? 1.f : 2.f;
    float lsum = 0.f;
#pragma unroll
    for (int i = 0; i < 4; ++i) {
#pragma unroll
        for (int r = 0; r < 4; ++r) {
            int rowl = wrow * 64 + i * 16 + fq * 4 + r;
            float ror = rn[0][rowl], rgr = rn[2][rowl];
#pragma unroll
            for (int j = 0; j < 4; ++j) {
                float so = acc_o[i][j][r] * ror * co[j];
                float st = acc_t[i][j][r] * rgr * cg[j];
                lsum += fabsf(so - st);
            }
        }
    }
    lsum *= w2;
#pragma unroll
    for (int off = 32; off > 0; off >>= 1) lsum += __shfl_down(lsum, off, 64);
    if (lane == 0) wred[wid] = lsum;
    __syncthreads();
    if (tid == 0)
        atomicAdd(&accum[pair * 32 + (bid0 & 31)], wred[0] + wred[1] + wred[2] + wred[3]);
}

__global__ void finalize_kernel(const float* __restrict__ a, float* __restrict__ out) {
    float s = a[threadIdx.x];
#pragma unroll
    for (int off = 32; off > 0; off >>= 1) s += __shfl_down(s, off, 64);
    if (threadIdx.x == 0) out[0] = s * (1.0f / 42467328.0f);  // mean over 8*2304^2, x2
}

extern "C" void kernel_launch(void* const* d_in, const int* in_sizes, int n_in,
                              void* d_out, int out_size, void* d_ws, size_t ws_size,
                              hipStream_t stream) {
    const float* o0 = (const float*)d_in[0];
    const float* o1 = (const float*)d_in[1];
    const float* t0 = (const float*)d_in[2];
    const float* t1 = (const float*)d_in[3];

    ushort* xtw  = (ushort*)d_ws;                                   // 18,874,368 B
    float*  rinv = (float*)((char*)d_ws + (size_t)4 * 8 * N_SP * 256);
    float*  accum = rinv + 4 * 8 * N_SP;                            // 64 floats

    prep_kernel<<<1152, 256, 0, stream>>>(o0, o1, t0, t1, xtw, rinv, accum);
    gram_kernel<<<NTILES, 256, 0, stream>>>(xtw, rinv, accum);
    finalize_kernel<<<1, 64, 0, stream>>>(accum, (float*)d_out);
}